// Round 16
// baseline (65.067 us; speedup 1.0000x reference)
//
#include <hip/hip_runtime.h>
#include <math.h>

#define N_ATOMS 512
#define N_MOL   16
#define HIDDEN  128
#define FILTERS 128
#define NUM_RBF 50
#define CUTOFF  10.0f
#define N_LAYERS 3

#define KB1    1024                  // nearest-neighbor bins over [0,10]
#define NB1    (KB1 + 1)             // rows 0..1024 (row 1024 = zeros via env)
#define TBPL   33                    // table blocks per layer (33*32 >= 1025 bins)
#define TBLK   (N_LAYERS * TBPL)     // 99 table blocks
#define EMBB   16                    // emb blocks, 32 atoms each
#define PI_F   3.14159265358979f
#define DINV   102.4f                // KB1 / CUTOFF
#define DSTEP  (CUTOFF / (float)KB1)
#define TAB_U4 ((NB1 * FILTERS * 2) / 16)   // 16400 uint4 per layer slice

__device__ __forceinline__ unsigned short f2bf(float v) {
    unsigned u = __float_as_uint(v);
    u += 0x7fffu + ((u >> 16) & 1u);     // round-to-nearest-even
    return (unsigned short)(u >> 16);
}
__device__ __forceinline__ float bflo(unsigned int u) { return __uint_as_float(u << 16); }
__device__ __forceinline__ float bfhi(unsigned int u) { return __uint_as_float(u & 0xffff0000u); }

// ====== front: filter tables as per-block fused GEMM (32 bins/block) ∥ embedding+xj0 ======
__global__ void __launch_bounds__(256) k_front(
        const int* __restrict__ an, const float* __restrict__ emb,
        const float* __restrict__ d1w, const float* __restrict__ d1b,
        const float* __restrict__ fw1, const float* __restrict__ fb1,
        const float* __restrict__ fw2, const float* __restrict__ fb2,
        float* __restrict__ x, unsigned short* __restrict__ xj,
        unsigned short* __restrict__ tab, float* __restrict__ molsum,
        int* __restrict__ done) {
    __shared__ float s_rbf[32][NUM_RBF];
    __shared__ __align__(16) float s_H[32][132];
    __shared__ __align__(16) float s_row[32][HIDDEN];
    __shared__ int   s_an[32];
    int bid = blockIdx.x, t = threadIdx.x;

    if (bid == 0) {
        for (int idx = t; idx < N_MOL * HIDDEN; idx += 256) molsum[idx] = 0.f;
        if (t < 4) done[t] = 0;
    }

    int cq = t & 31, ag = t >> 5;

    if (bid < TBLK) {
        int l = bid / TBPL, bx = bid - l * TBPL;
        int bin0 = bx * 32;
        const float* w1g = fw1 + (size_t)l * NUM_RBF * FILTERS;
        const float* w2g = fw2 + (size_t)l * FILTERS * FILTERS;
        for (int idx = t; idx < 32 * NUM_RBF; idx += 256) {
            int lb = idx / NUM_RBF, r = idx - lb * NUM_RBF;
            float dd = (bin0 + lb) * DSTEP;
            float cr = r * (CUTOFF / (float)(NUM_RBF - 1));
            float xx = dd - cr;
            s_rbf[lb][r] = __expf(-xx * xx * 12.5f);     // 1/(2*w^2), w = 0.2
        }
        __syncthreads();
        {
            float h[4][4];
            float4 bv = *(const float4*)(fb1 + (size_t)l * FILTERS + 4 * cq);
            float bva[4] = { bv.x, bv.y, bv.z, bv.w };
            #pragma unroll
            for (int aa = 0; aa < 4; aa++)
                #pragma unroll
                for (int cc = 0; cc < 4; cc++) h[aa][cc] = bva[cc];
            #pragma unroll 2
            for (int r = 0; r < NUM_RBF; r++) {
                float4 w = *(const float4*)(w1g + (size_t)r * FILTERS + 4 * cq);
                float wa[4] = { w.x, w.y, w.z, w.w };
                #pragma unroll
                for (int aa = 0; aa < 4; aa++) {
                    float rb = s_rbf[ag * 4 + aa][r];
                    #pragma unroll
                    for (int cc = 0; cc < 4; cc++) h[aa][cc] = fmaf(rb, wa[cc], h[aa][cc]);
                }
            }
            __syncthreads();
            #pragma unroll
            for (int aa = 0; aa < 4; aa++) {
                float4 sv;
                sv.x = h[aa][0] / (1.f + __expf(-h[aa][0]));
                sv.y = h[aa][1] / (1.f + __expf(-h[aa][1]));
                sv.z = h[aa][2] / (1.f + __expf(-h[aa][2]));
                sv.w = h[aa][3] / (1.f + __expf(-h[aa][3]));
                *(float4*)(&s_H[ag * 4 + aa][4 * cq]) = sv;
            }
        }
        __syncthreads();
        float o[4][4];
        float4 b2v = *(const float4*)(fb2 + (size_t)l * FILTERS + 4 * cq);
        float b2a[4] = { b2v.x, b2v.y, b2v.z, b2v.w };
        #pragma unroll
        for (int aa = 0; aa < 4; aa++)
            #pragma unroll
            for (int cc = 0; cc < 4; cc++) o[aa][cc] = b2a[cc];
        #pragma unroll 4
        for (int hh = 0; hh < FILTERS; hh += 2) {
            float4 wA = *(const float4*)(w2g + (size_t)hh * FILTERS + 4 * cq);
            float4 wB = *(const float4*)(w2g + (size_t)(hh + 1) * FILTERS + 4 * cq);
            float wa[4] = { wA.x, wA.y, wA.z, wA.w };
            float wb[4] = { wB.x, wB.y, wB.z, wB.w };
            #pragma unroll
            for (int aa = 0; aa < 4; aa++) {
                float2 hp = *(const float2*)(&s_H[ag * 4 + aa][hh]);
                #pragma unroll
                for (int cc = 0; cc < 4; cc++) {
                    o[aa][cc] = fmaf(hp.x, wa[cc], o[aa][cc]);
                    o[aa][cc] = fmaf(hp.y, wb[cc], o[aa][cc]);
                }
            }
        }
        size_t base = (size_t)l * NB1 * FILTERS;
        #pragma unroll
        for (int aa = 0; aa < 4; aa++) {
            int bin = bin0 + ag * 4 + aa;
            if (bin <= KB1) {
                float dd = bin * DSTEP;
                float env = (bin >= KB1) ? 0.f : 0.5f * (__cosf(dd * (PI_F / CUTOFF)) + 1.f);
                #pragma unroll
                for (int cp = 0; cp < 2; cp++) {
                    unsigned int pk = (unsigned)f2bf(o[aa][2 * cp] * env) |
                                      ((unsigned)f2bf(o[aa][2 * cp + 1] * env) << 16);
                    *(unsigned int*)(tab + base + (size_t)bin * FILTERS + 4 * cq + 2 * cp) = pk;
                }
            }
        }
    } else {
        int eb = bid - TBLK;
        int i0 = eb * 32;
        if (t < 32) s_an[t] = an[i0 + t];
        __syncthreads();
        for (int idx = t; idx < 32 * HIDDEN; idx += 256) {
            int a = idx >> 7, c = idx & 127;
            float v = emb[(size_t)s_an[a] * HIDDEN + c];
            s_row[a][c] = v;
            x[(size_t)(i0 + a) * HIDDEN + c] = v;
        }
        __syncthreads();
        float o[4][4];
        float4 bv = *(const float4*)(d1b + 4 * cq);
        float bva[4] = { bv.x, bv.y, bv.z, bv.w };
        #pragma unroll
        for (int aa = 0; aa < 4; aa++)
            #pragma unroll
            for (int cc = 0; cc < 4; cc++) o[aa][cc] = bva[cc];
        #pragma unroll 4
        for (int h = 0; h < HIDDEN; h += 2) {
            float4 wA = *(const float4*)(d1w + (size_t)h * FILTERS + 4 * cq);
            float4 wB = *(const float4*)(d1w + (size_t)(h + 1) * FILTERS + 4 * cq);
            float wa[4] = { wA.x, wA.y, wA.z, wA.w };
            float wb[4] = { wB.x, wB.y, wB.z, wB.w };
            #pragma unroll
            for (int aa = 0; aa < 4; aa++) {
                float2 hp = *(const float2*)(&s_row[ag * 4 + aa][h]);
                #pragma unroll
                for (int cc = 0; cc < 4; cc++) {
                    o[aa][cc] = fmaf(hp.x, wa[cc], o[aa][cc]);
                    o[aa][cc] = fmaf(hp.y, wb[cc], o[aa][cc]);
                }
            }
        }
        #pragma unroll
        for (int aa = 0; aa < 4; aa++) {
            int i = i0 + ag * 4 + aa;
            #pragma unroll
            for (int cp = 0; cp < 2; cp++) {
                unsigned int pk = (unsigned)f2bf(o[aa][2 * cp]) |
                                  ((unsigned)f2bf(o[aa][2 * cp + 1]) << 16);
                *(unsigned int*)(xj + (size_t)i * FILTERS + 4 * cq + 2 * cp) = pk;
            }
        }
    }
}

// ======== layer: 1 j per block, 512 blocks; 4ch/lane uint2 gather (2 rows per wave-step) ====
template<int LAST>
__global__ void __launch_bounds__(512) k_layer(const float* __restrict__ pos,
        const unsigned int* __restrict__ tabl, const unsigned int* __restrict__ xj_in,
        float* __restrict__ x, const float* __restrict__ w2, const float* __restrict__ b2,
        const float* __restrict__ w1n, const float* __restrict__ b1n,
        unsigned int* __restrict__ xj_out,
        const int* __restrict__ batch, float* __restrict__ molsum, int* __restrict__ done,
        const float* __restrict__ ow1, const float* __restrict__ ob1,
        const float* __restrict__ ow2, const float* __restrict__ ob2,
        float* __restrict__ out) {
    int j = blockIdx.x, t = threadIdx.x;
    int wv = t >> 6, e = t & 63;
    __shared__ unsigned short s_bin[N_ATOMS];
    __shared__ float s_part[8][FILTERS];
    __shared__ float s_red[4][FILTERS];
    __shared__ float s_agg[FILTERS];
    __shared__ float s_xn[HIDDEN];
    __shared__ int   s_tick;
    __shared__ float s_mol[16][HIDDEN];
    __shared__ float s_h[16][64];
    __shared__ int   s_c16[16];
    {   // one distance per thread (i = t vs this block's j)
        float px = pos[3*t], py = pos[3*t+1], pz = pos[3*t+2];
        float ax = pos[3*j], ay = pos[3*j+1], az = pos[3*j+2];
        float d = sqrtf((px-ax)*(px-ax) + (py-ay)*(py-ay) + (pz-az)*(pz-az));
        unsigned int b = (t == j || d >= CUTOFF) ? KB1 : (unsigned)(int)fmaf(d, DINV, 0.5f);
        if (b > KB1) b = KB1;
        s_bin[t] = (unsigned short)b;
    }
    int c = t & 127, seg = t >> 7;
    float xold = (seg == 0) ? x[(size_t)j * HIDDEN + c] : 0.f;
    {   // L2 warm: stream this block's tab slice (perf-only)
        const uint4* t4 = (const uint4*)tabl;
        int slice = j & 31;
        int q0 = slice * 513;
        int qe = q0 + 513; if (qe > TAB_U4) qe = TAB_U4;
        unsigned int acc = 0;
        for (int q = q0 + t; q < qe; q += 512) {
            uint4 w = t4[q];
            acc ^= w.x ^ w.y ^ w.z ^ w.w;
        }
        asm volatile("" :: "v"(acc));
    }
    __syncthreads();
    // ---- aggregation: wave wv covers i in [wv*64,+64); lane-half h rows i+h,
    //      32 lanes x 4ch (uint2 = 4 bf16) cover all 128 channels ----
    {
        int h = e >> 5, cq4 = e & 31;
        const uint2* tb2 = (const uint2*)tabl;           // row = 32 uint2
        const uint2* xj2 = (const uint2*)xj_in;
        float a0 = 0.f, a1 = 0.f, a2 = 0.f, a3 = 0.f;
        int i0 = wv * 64;
        for (int ii = 0; ii < 64; ii += 8) {
            #pragma unroll
            for (int r = 0; r < 8; r += 2) {
                int i = i0 + ii + r + h;
                int bb = s_bin[i];
                uint2 f  = tb2[(size_t)bb * 32 + cq4];
                uint2 xu = xj2[(size_t)i  * 32 + cq4];
                a0 = fmaf(bflo(xu.x), bflo(f.x), a0);
                a1 = fmaf(bfhi(xu.x), bfhi(f.x), a1);
                a2 = fmaf(bflo(xu.y), bflo(f.y), a2);
                a3 = fmaf(bfhi(xu.y), bfhi(f.y), a3);
            }
        }
        a0 += __shfl_down(a0, 32, 64);
        a1 += __shfl_down(a1, 32, 64);
        a2 += __shfl_down(a2, 32, 64);
        a3 += __shfl_down(a3, 32, 64);
        if (h == 0) {
            s_part[wv][4*cq4+0] = a0;
            s_part[wv][4*cq4+1] = a1;
            s_part[wv][4*cq4+2] = a2;
            s_part[wv][4*cq4+3] = a3;
        }
    }
    __syncthreads();
    if (t < FILTERS) {
        float s = 0.f;
        #pragma unroll
        for (int w8 = 0; w8 < 8; w8++) s += s_part[w8][t];
        s_agg[t] = s;
    }
    __syncthreads();
    // ---- x update: 128-dot split over 4 segments of 32 ----
    float v = 0.f;
    #pragma unroll 8
    for (int ff = seg * 32; ff < seg * 32 + 32; ff++)
        v = fmaf(s_agg[ff], w2[(size_t)ff * HIDDEN + c], v);
    s_red[seg][c] = v;
    __syncthreads();
    float xnew = 0.f;
    if (seg == 0) {
        xnew = xold + b2[c] + s_red[0][c] + s_red[1][c] + s_red[2][c] + s_red[3][c];
        x[(size_t)j * HIDDEN + c] = xnew;
        s_xn[c] = xnew;
    }
    __syncthreads();
    if (!LAST) {
        float a2 = 0.f;
        #pragma unroll 8
        for (int hh = seg * 32; hh < seg * 32 + 32; hh++)
            a2 = fmaf(s_xn[hh], w1n[(size_t)hh * FILTERS + c], a2);
        s_red[seg][c] = a2;
        __syncthreads();
        if (t < 64) {                                    // pack 2 ch per lane
            float v0 = b1n[2*t]   + s_red[0][2*t]   + s_red[1][2*t]   + s_red[2][2*t]   + s_red[3][2*t];
            float v1 = b1n[2*t+1] + s_red[0][2*t+1] + s_red[1][2*t+1] + s_red[2][2*t+1] + s_red[3][2*t+1];
            xj_out[(size_t)j * 64 + t] = (unsigned)f2bf(v0) | ((unsigned)f2bf(v1) << 16);
        }
    } else {
        // ---- pool: molsum adds, then LAST ticket-holder computes all 16 molecules ----
        if (seg == 0) atomicAdd(&molsum[(size_t)batch[j] * HIDDEN + c], xnew);
        __syncthreads();                                 // drains vmcnt (adds at coherence pt)
        if (t == 0) s_tick = atomicAdd(&done[0], 1);
        __syncthreads();
        if (s_tick == (int)gridDim.x - 1) {              // provably last: all adds precede
            if (t < 16) s_c16[t] = 0;
            __syncthreads();
            atomicAdd(&s_c16[batch[t]], 1);              // histogram over 512 atoms
            __syncthreads();
            #pragma unroll
            for (int mo = 0; mo < 4; mo++) {
                int m = mo * 4 + seg;
                float sv = atomicAdd(&molsum[(size_t)m * HIDDEN + c], 0.f);
                int cnt = s_c16[m];
                s_mol[m][c] = sv / (float)(cnt > 0 ? cnt : 1);
            }
            __syncthreads();
            #pragma unroll
            for (int rr = 0; rr < 2; rr++) {             // 1024 MLP1 outputs, 2/thread
                int o = t + rr * 512;
                int m = o >> 6, k = o & 63;
                float a = ob1[k];
                #pragma unroll 8
                for (int h = 0; h < HIDDEN; h++) a = fmaf(s_mol[m][h], ow1[h * 64 + k], a);
                s_h[m][k] = a / (1.f + __expf(-a));      // silu
            }
            __syncthreads();
            if (t < N_MOL) {
                float a = ob2[0];
                #pragma unroll 8
                for (int h = 0; h < 64; h++) a = fmaf(s_h[t][h], ow2[h], a);
                out[t] = a;
            }
        }
    }
}

extern "C" void kernel_launch(void* const* d_in, const int* in_sizes, int n_in,
                              void* d_out, int out_size, void* d_ws, size_t ws_size,
                              hipStream_t stream) {
    const int*   an    = (const int*)  d_in[0];
    const float* pos   = (const float*)d_in[1];
    const int*   batch = (const int*)  d_in[2];
    const float* emb   = (const float*)d_in[3];
    const float* fw1   = (const float*)d_in[4];
    const float* fb1   = (const float*)d_in[5];
    const float* fw2   = (const float*)d_in[6];
    const float* fb2   = (const float*)d_in[7];
    const float* d1w   = (const float*)d_in[8];
    const float* d1b   = (const float*)d_in[9];
    const float* d2w   = (const float*)d_in[10];
    const float* d2b   = (const float*)d_in[11];
    const float* ow1   = (const float*)d_in[12];
    const float* ob1   = (const float*)d_in[13];
    const float* ow2   = (const float*)d_in[14];
    const float* ob2   = (const float*)d_in[15];
    float* out = (float*)d_out;

    float*          x    = (float*)d_ws;                               // 256 KB
    unsigned int*   xj0  = (unsigned int*)(x + N_ATOMS * HIDDEN);      // 128 KB
    unsigned int*   xj1  = xj0 + (size_t)N_ATOMS * 64;                 // 128 KB
    unsigned int*   xj2  = xj1 + (size_t)N_ATOMS * 64;                 // 128 KB
    unsigned short* tab  = (unsigned short*)(xj2 + (size_t)N_ATOMS * 64);  // 3*1025*256B
    float*          mols = (float*)(tab + (size_t)N_LAYERS * NB1 * FILTERS);
    int*            done = (int*)(mols + N_MOL * HIDDEN);

    k_front<<<TBLK + EMBB, 256, 0, stream>>>(
        an, emb, d1w, d1b, fw1, fb1, fw2, fb2, x, (unsigned short*)xj0, tab, mols, done);

    const unsigned int* t0 = (const unsigned int*)(tab + (size_t)0 * NB1 * FILTERS);
    const unsigned int* t1 = (const unsigned int*)(tab + (size_t)1 * NB1 * FILTERS);
    const unsigned int* t2 = (const unsigned int*)(tab + (size_t)2 * NB1 * FILTERS);

    k_layer<0><<<N_ATOMS, 512, 0, stream>>>(pos, t0, xj0, x,
        d2w + (size_t)0*FILTERS*HIDDEN, d2b + (size_t)0*HIDDEN,
        d1w + (size_t)1*HIDDEN*FILTERS, d1b + (size_t)1*FILTERS, xj1,
        batch, mols, done, ow1, ob1, ow2, ob2, out);
    k_layer<0><<<N_ATOMS, 512, 0, stream>>>(pos, t1, xj1, x,
        d2w + (size_t)1*FILTERS*HIDDEN, d2b + (size_t)1*HIDDEN,
        d1w + (size_t)2*HIDDEN*FILTERS, d1b + (size_t)2*FILTERS, xj2,
        batch, mols, done, ow1, ob1, ow2, ob2, out);
    k_layer<1><<<N_ATOMS, 512, 0, stream>>>(pos, t2, xj2, x,
        d2w + (size_t)2*FILTERS*HIDDEN, d2b + (size_t)2*HIDDEN,
        d1w, d1b, xj0,
        batch, mols, done, ow1, ob1, ow2, ob2, out);
}

// Round 17
// 59.533 us; speedup vs baseline: 1.0930x; 1.0930x over previous
//
#include <hip/hip_runtime.h>
#include <math.h>

#define N_ATOMS 512
#define N_MOL   16
#define HIDDEN  128
#define FILTERS 128
#define NUM_RBF 50
#define CUTOFF  10.0f
#define N_LAYERS 3

#define KB2    2048                  // nearest-neighbor bins over [0,10]
#define NB2    (KB2 + 1)             // rows 0..2048 (row 2048 ~ zeros via env)
#define TBPL   65                    // table blocks per layer (65*32 >= 2049 bins)
#define TBLK   (N_LAYERS * TBPL)     // 195 table blocks
#define EMBB   16                    // emb blocks, 32 atoms each
#define PI_F   3.14159265358979f
#define DINV   204.8f                // KB2 / CUTOFF
#define DSTEP  (CUTOFF / (float)KB2)
#define TAB_U4 ((NB2 * 64) / 4)      // uint4 count per layer slice (32784)

__device__ __forceinline__ unsigned short f2bf(float v) {
    unsigned u = __float_as_uint(v);
    u += 0x7fffu + ((u >> 16) & 1u);     // round-to-nearest-even
    return (unsigned short)(u >> 16);
}

// ====== front: filter tables as per-block fused GEMM (32 bins/block) ∥ embedding+xj0 ======
__global__ void __launch_bounds__(256) k_front(
        const int* __restrict__ an, const float* __restrict__ emb,
        const float* __restrict__ d1w, const float* __restrict__ d1b,
        const float* __restrict__ fw1, const float* __restrict__ fb1,
        const float* __restrict__ fw2, const float* __restrict__ fb2,
        float* __restrict__ x, unsigned short* __restrict__ xj,
        unsigned short* __restrict__ tab, float* __restrict__ molsum,
        int* __restrict__ done) {
    __shared__ float s_rbf[32][NUM_RBF];
    __shared__ __align__(16) float s_H[32][132];
    __shared__ __align__(16) float s_row[32][HIDDEN];
    __shared__ int   s_an[32];
    int bid = blockIdx.x, t = threadIdx.x;

    if (bid == 0) {
        for (int idx = t; idx < N_MOL * HIDDEN; idx += 256) molsum[idx] = 0.f;
        if (t < 4) done[t] = 0;
    }

    int cq = t & 31, ag = t >> 5;

    if (bid < TBLK) {
        int l = bid / TBPL, bx = bid - l * TBPL;
        int bin0 = bx * 32;
        const float* w1g = fw1 + (size_t)l * NUM_RBF * FILTERS;
        const float* w2g = fw2 + (size_t)l * FILTERS * FILTERS;
        for (int idx = t; idx < 32 * NUM_RBF; idx += 256) {
            int lb = idx / NUM_RBF, r = idx - lb * NUM_RBF;
            float dd = (bin0 + lb) * DSTEP;
            float cr = r * (CUTOFF / (float)(NUM_RBF - 1));
            float xx = dd - cr;
            s_rbf[lb][r] = __expf(-xx * xx * 12.5f);     // 1/(2*w^2), w = 0.2
        }
        __syncthreads();
        {
            float h[4][4];
            float4 bv = *(const float4*)(fb1 + (size_t)l * FILTERS + 4 * cq);
            float bva[4] = { bv.x, bv.y, bv.z, bv.w };
            #pragma unroll
            for (int aa = 0; aa < 4; aa++)
                #pragma unroll
                for (int cc = 0; cc < 4; cc++) h[aa][cc] = bva[cc];
            #pragma unroll 2
            for (int r = 0; r < NUM_RBF; r++) {
                float4 w = *(const float4*)(w1g + (size_t)r * FILTERS + 4 * cq);
                float wa[4] = { w.x, w.y, w.z, w.w };
                #pragma unroll
                for (int aa = 0; aa < 4; aa++) {
                    float rb = s_rbf[ag * 4 + aa][r];
                    #pragma unroll
                    for (int cc = 0; cc < 4; cc++) h[aa][cc] = fmaf(rb, wa[cc], h[aa][cc]);
                }
            }
            __syncthreads();
            #pragma unroll
            for (int aa = 0; aa < 4; aa++) {
                float4 sv;
                sv.x = h[aa][0] / (1.f + __expf(-h[aa][0]));
                sv.y = h[aa][1] / (1.f + __expf(-h[aa][1]));
                sv.z = h[aa][2] / (1.f + __expf(-h[aa][2]));
                sv.w = h[aa][3] / (1.f + __expf(-h[aa][3]));
                *(float4*)(&s_H[ag * 4 + aa][4 * cq]) = sv;
            }
        }
        __syncthreads();
        float o[4][4];
        float4 b2v = *(const float4*)(fb2 + (size_t)l * FILTERS + 4 * cq);
        float b2a[4] = { b2v.x, b2v.y, b2v.z, b2v.w };
        #pragma unroll
        for (int aa = 0; aa < 4; aa++)
            #pragma unroll
            for (int cc = 0; cc < 4; cc++) o[aa][cc] = b2a[cc];
        #pragma unroll 4
        for (int hh = 0; hh < FILTERS; hh += 2) {
            float4 wA = *(const float4*)(w2g + (size_t)hh * FILTERS + 4 * cq);
            float4 wB = *(const float4*)(w2g + (size_t)(hh + 1) * FILTERS + 4 * cq);
            float wa[4] = { wA.x, wA.y, wA.z, wA.w };
            float wb[4] = { wB.x, wB.y, wB.z, wB.w };
            #pragma unroll
            for (int aa = 0; aa < 4; aa++) {
                float2 hp = *(const float2*)(&s_H[ag * 4 + aa][hh]);
                #pragma unroll
                for (int cc = 0; cc < 4; cc++) {
                    o[aa][cc] = fmaf(hp.x, wa[cc], o[aa][cc]);
                    o[aa][cc] = fmaf(hp.y, wb[cc], o[aa][cc]);
                }
            }
        }
        size_t base = (size_t)l * NB2 * FILTERS;
        #pragma unroll
        for (int aa = 0; aa < 4; aa++) {
            int bin = bin0 + ag * 4 + aa;
            if (bin <= KB2) {
                float dd = bin * DSTEP;
                float env = (bin >= KB2) ? 0.f : 0.5f * (__cosf(dd * (PI_F / CUTOFF)) + 1.f);
                #pragma unroll
                for (int cp = 0; cp < 2; cp++) {
                    unsigned int pk = (unsigned)f2bf(o[aa][2 * cp] * env) |
                                      ((unsigned)f2bf(o[aa][2 * cp + 1] * env) << 16);
                    *(unsigned int*)(tab + base + (size_t)bin * FILTERS + 4 * cq + 2 * cp) = pk;
                }
            }
        }
    } else {
        int eb = bid - TBLK;
        int i0 = eb * 32;
        if (t < 32) s_an[t] = an[i0 + t];
        __syncthreads();
        for (int idx = t; idx < 32 * HIDDEN; idx += 256) {
            int a = idx >> 7, c = idx & 127;
            float v = emb[(size_t)s_an[a] * HIDDEN + c];
            s_row[a][c] = v;
            x[(size_t)(i0 + a) * HIDDEN + c] = v;
        }
        __syncthreads();
        float o[4][4];
        float4 bv = *(const float4*)(d1b + 4 * cq);
        float bva[4] = { bv.x, bv.y, bv.z, bv.w };
        #pragma unroll
        for (int aa = 0; aa < 4; aa++)
            #pragma unroll
            for (int cc = 0; cc < 4; cc++) o[aa][cc] = bva[cc];
        #pragma unroll 4
        for (int h = 0; h < HIDDEN; h += 2) {
            float4 wA = *(const float4*)(d1w + (size_t)h * FILTERS + 4 * cq);
            float4 wB = *(const float4*)(d1w + (size_t)(h + 1) * FILTERS + 4 * cq);
            float wa[4] = { wA.x, wA.y, wA.z, wA.w };
            float wb[4] = { wB.x, wB.y, wB.z, wB.w };
            #pragma unroll
            for (int aa = 0; aa < 4; aa++) {
                float2 hp = *(const float2*)(&s_row[ag * 4 + aa][h]);
                #pragma unroll
                for (int cc = 0; cc < 4; cc++) {
                    o[aa][cc] = fmaf(hp.x, wa[cc], o[aa][cc]);
                    o[aa][cc] = fmaf(hp.y, wb[cc], o[aa][cc]);
                }
            }
        }
        #pragma unroll
        for (int aa = 0; aa < 4; aa++) {
            int i = i0 + ag * 4 + aa;
            #pragma unroll
            for (int cp = 0; cp < 2; cp++) {
                unsigned int pk = (unsigned)f2bf(o[aa][2 * cp]) |
                                  ((unsigned)f2bf(o[aa][2 * cp + 1]) << 16);
                *(unsigned int*)(xj + (size_t)i * FILTERS + 4 * cq + 2 * cp) = pk;
            }
        }
    }
}

// ======== layer: 1 j per block, 512 blocks (16 waves/CU); L2-warm pass; last-ticket pool ====
template<int LAST>
__global__ void __launch_bounds__(512) k_layer(const float* __restrict__ pos,
        const unsigned int* __restrict__ tabl, const unsigned int* __restrict__ xj_in,
        float* __restrict__ x, const float* __restrict__ w2, const float* __restrict__ b2,
        const float* __restrict__ w1n, const float* __restrict__ b1n,
        unsigned int* __restrict__ xj_out,
        const int* __restrict__ batch, float* __restrict__ molsum, int* __restrict__ done,
        const float* __restrict__ ow1, const float* __restrict__ ob1,
        const float* __restrict__ ow2, const float* __restrict__ ob2,
        float* __restrict__ out) {
    int j = blockIdx.x, t = threadIdx.x;
    int wv = t >> 6, e = t & 63;
    __shared__ unsigned short s_bin[N_ATOMS];            // 1 KB
    __shared__ float s_part[8][FILTERS];                 // 4 KB
    __shared__ float s_red[4][FILTERS];                  // 2 KB
    __shared__ float s_agg[FILTERS];
    __shared__ float s_xn[HIDDEN];
    __shared__ int   s_tick;
    __shared__ float s_mol[16][HIDDEN];                  // finisher only (8 KB)
    __shared__ float s_h[16][64];                        // finisher only (4 KB)
    __shared__ int   s_c16[16];
    {   // one distance per thread (i = t vs this block's j)
        float px = pos[3*t], py = pos[3*t+1], pz = pos[3*t+2];
        float ax = pos[3*j], ay = pos[3*j+1], az = pos[3*j+2];
        float d = sqrtf((px-ax)*(px-ax) + (py-ay)*(py-ay) + (pz-az)*(pz-az));
        unsigned int b = (t == j || d >= CUTOFF) ? KB2 : (unsigned)(int)fmaf(d, DINV, 0.5f);
        if (b > KB2) b = KB2;
        s_bin[t] = (unsigned short)b;
    }
    int c = t & 127, seg = t >> 7;
    float xold = (seg == 0) ? x[(size_t)j * HIDDEN + c] : 0.f;
    {   // L2 warm: stream this block's tab slice (perf-only; XCD round-robin heuristic)
        const uint4* t4 = (const uint4*)tabl;
        int slice = (j >> 3) & 31;
        int q0 = slice * 1025;
        int qe = q0 + 1025; if (qe > TAB_U4) qe = TAB_U4;
        unsigned int acc = 0;
        for (int q = q0 + t; q < qe; q += 512) {
            uint4 w = t4[q];
            acc ^= w.x ^ w.y ^ w.z ^ w.w;
        }
        asm volatile("" :: "v"(acc));                    // keep warm loads live (rule #17)
    }
    __syncthreads();
    // ---- aggregation: wave wv covers i in [wv*64,+64); lane e owns channels {2e,2e+1} ----
    float ae = 0.f, ao = 0.f;
    int i0 = wv * 64;
    for (int ii = 0; ii < 64; ii += 8) {
        #pragma unroll
        for (int r = 0; r < 8; r++) {
            int bb = s_bin[i0 + ii + r];
            unsigned int xu = xj_in[(size_t)(i0 + ii + r) * 64 + e];
            unsigned int f  = tabl[(size_t)bb * 64 + e];
            float xe = __uint_as_float(xu << 16), xo = __uint_as_float(xu & 0xffff0000u);
            float pe = __uint_as_float(f << 16),  po = __uint_as_float(f & 0xffff0000u);
            ae = fmaf(xe, pe, ae);
            ao = fmaf(xo, po, ao);
        }
    }
    s_part[wv][2*e] = ae;  s_part[wv][2*e+1] = ao;
    __syncthreads();
    if (t < FILTERS) {
        float s = 0.f;
        #pragma unroll
        for (int w8 = 0; w8 < 8; w8++) s += s_part[w8][t];
        s_agg[t] = s;
    }
    __syncthreads();
    // ---- x update: 128-dot split over 4 segments of 32 ----
    float v = 0.f;
    #pragma unroll 8
    for (int ff = seg * 32; ff < seg * 32 + 32; ff++)
        v = fmaf(s_agg[ff], w2[(size_t)ff * HIDDEN + c], v);
    s_red[seg][c] = v;
    __syncthreads();
    float xnew = 0.f;
    if (seg == 0) {
        xnew = xold + b2[c] + s_red[0][c] + s_red[1][c] + s_red[2][c] + s_red[3][c];
        x[(size_t)j * HIDDEN + c] = xnew;
        s_xn[c] = xnew;
    }
    __syncthreads();
    if (!LAST) {
        float a2 = 0.f;
        #pragma unroll 8
        for (int hh = seg * 32; hh < seg * 32 + 32; hh++)
            a2 = fmaf(s_xn[hh], w1n[(size_t)hh * FILTERS + c], a2);
        s_red[seg][c] = a2;
        __syncthreads();
        if (t < 64) {                                    // pack 2 ch per lane
            float v0 = b1n[2*t]   + s_red[0][2*t]   + s_red[1][2*t]   + s_red[2][2*t]   + s_red[3][2*t];
            float v1 = b1n[2*t+1] + s_red[0][2*t+1] + s_red[1][2*t+1] + s_red[2][2*t+1] + s_red[3][2*t+1];
            xj_out[(size_t)j * 64 + t] = (unsigned)f2bf(v0) | ((unsigned)f2bf(v1) << 16);
        }
    } else {
        // ---- pool: molsum adds, then LAST ticket-holder computes all 16 molecules ----
        if (seg == 0) atomicAdd(&molsum[(size_t)batch[j] * HIDDEN + c], xnew);
        __syncthreads();                                 // drains vmcnt (adds at coherence pt)
        if (t == 0) s_tick = atomicAdd(&done[0], 1);
        __syncthreads();
        if (s_tick == (int)gridDim.x - 1) {              // provably last: all adds precede
            if (t < 16) s_c16[t] = 0;
            __syncthreads();
            atomicAdd(&s_c16[batch[t]], 1);              // histogram over 512 atoms
            __syncthreads();
            #pragma unroll
            for (int mo = 0; mo < 4; mo++) {
                int m = mo * 4 + seg;
                float sv = atomicAdd(&molsum[(size_t)m * HIDDEN + c], 0.f);
                int cnt = s_c16[m];
                s_mol[m][c] = sv / (float)(cnt > 0 ? cnt : 1);
            }
            __syncthreads();
            #pragma unroll
            for (int rr = 0; rr < 2; rr++) {             // 1024 MLP1 outputs, 2/thread
                int o = t + rr * 512;
                int m = o >> 6, k = o & 63;
                float a = ob1[k];
                #pragma unroll 8
                for (int h = 0; h < HIDDEN; h++) a = fmaf(s_mol[m][h], ow1[h * 64 + k], a);
                s_h[m][k] = a / (1.f + __expf(-a));      // silu
            }
            __syncthreads();
            if (t < N_MOL) {
                float a = ob2[0];
                #pragma unroll 8
                for (int h = 0; h < 64; h++) a = fmaf(s_h[t][h], ow2[h], a);
                out[t] = a;
            }
        }
    }
}

extern "C" void kernel_launch(void* const* d_in, const int* in_sizes, int n_in,
                              void* d_out, int out_size, void* d_ws, size_t ws_size,
                              hipStream_t stream) {
    const int*   an    = (const int*)  d_in[0];
    const float* pos   = (const float*)d_in[1];
    const int*   batch = (const int*)  d_in[2];
    const float* emb   = (const float*)d_in[3];
    const float* fw1   = (const float*)d_in[4];
    const float* fb1   = (const float*)d_in[5];
    const float* fw2   = (const float*)d_in[6];
    const float* fb2   = (const float*)d_in[7];
    const float* d1w   = (const float*)d_in[8];
    const float* d1b   = (const float*)d_in[9];
    const float* d2w   = (const float*)d_in[10];
    const float* d2b   = (const float*)d_in[11];
    const float* ow1   = (const float*)d_in[12];
    const float* ob1   = (const float*)d_in[13];
    const float* ow2   = (const float*)d_in[14];
    const float* ob2   = (const float*)d_in[15];
    float* out = (float*)d_out;

    float*          x    = (float*)d_ws;                               // 256 KB
    unsigned int*   xj0  = (unsigned int*)(x + N_ATOMS * HIDDEN);      // 128 KB
    unsigned int*   xj1  = xj0 + (size_t)N_ATOMS * 64;                 // 128 KB
    unsigned int*   xj2  = xj1 + (size_t)N_ATOMS * 64;                 // 128 KB
    unsigned short* tab  = (unsigned short*)(xj2 + (size_t)N_ATOMS * 64);  // 1.54 MB
    float*          mols = (float*)(tab + (size_t)N_LAYERS * NB2 * FILTERS);
    int*            done = (int*)(mols + N_MOL * HIDDEN);

    k_front<<<TBLK + EMBB, 256, 0, stream>>>(
        an, emb, d1w, d1b, fw1, fb1, fw2, fb2, x, (unsigned short*)xj0, tab, mols, done);

    const unsigned int* t0 = (const unsigned int*)(tab + (size_t)0 * NB2 * FILTERS);
    const unsigned int* t1 = (const unsigned int*)(tab + (size_t)1 * NB2 * FILTERS);
    const unsigned int* t2 = (const unsigned int*)(tab + (size_t)2 * NB2 * FILTERS);

    k_layer<0><<<N_ATOMS, 512, 0, stream>>>(pos, t0, xj0, x,
        d2w + (size_t)0*FILTERS*HIDDEN, d2b + (size_t)0*HIDDEN,
        d1w + (size_t)1*HIDDEN*FILTERS, d1b + (size_t)1*FILTERS, xj1,
        batch, mols, done, ow1, ob1, ow2, ob2, out);
    k_layer<0><<<N_ATOMS, 512, 0, stream>>>(pos, t1, xj1, x,
        d2w + (size_t)1*FILTERS*HIDDEN, d2b + (size_t)1*HIDDEN,
        d1w + (size_t)2*HIDDEN*FILTERS, d1b + (size_t)2*FILTERS, xj2,
        batch, mols, done, ow1, ob1, ow2, ob2, out);
    k_layer<1><<<N_ATOMS, 512, 0, stream>>>(pos, t2, xj2, x,
        d2w + (size_t)2*FILTERS*HIDDEN, d2b + (size_t)2*HIDDEN,
        d1w, d1b, xj0,
        batch, mols, done, ow1, ob1, ow2, ob2, out);
}